// Round 3
// baseline (1364.241 us; speedup 1.0000x reference)
//
#include <hip/hip_runtime.h>

typedef unsigned short u16;
typedef __bf16 bf16x8 __attribute__((ext_vector_type(8)));
typedef float f32x4 __attribute__((ext_vector_type(4)));
typedef int i32x4 __attribute__((ext_vector_type(4)));

#define MFMA_BF16(a, b, c) __builtin_amdgcn_mfma_f32_16x16x32_bf16((a), (b), (c), 0, 0, 0)
#define COMPILER_FENCE() asm volatile("" ::: "memory")

__device__ __forceinline__ bf16x8 ld_g16(const __bf16* p) {
  return *(const bf16x8*)p;
}
__device__ __forceinline__ bf16x8 ld_s16(const __bf16* base, int byteoff) {
  return *(const bf16x8*)((const char*)base + byteoff);
}

// OUT[o][p] = sum_c W[o][c] * SRC[c][p], o in wave's 64-row band, p in 0..63.
// SRC in LDS position-major [p][c] bf16, rows 512B, XOR-swizzled by ((p&7)<<4).
__device__ __forceinline__ void proj_mfma(const __bf16* __restrict__ Wg,
                                          const __bf16* src, f32x4 (&acc)[4][4],
                                          int w, int lm, int lg)
{
  for (int ks = 0; ks < 8; ++ks) {
    bf16x8 afr[4], bfr[4];
#pragma unroll
    for (int mt = 0; mt < 4; ++mt)
      afr[mt] = ld_g16(Wg + (w * 64 + mt * 16 + lm) * 256 + ks * 32 + lg * 8);
#pragma unroll
    for (int nt = 0; nt < 4; ++nt) {
      int p = nt * 16 + lm;
      bfr[nt] = ld_s16(src, p * 512 + (((ks * 32 + lg * 8) * 2) ^ ((p & 7) << 4)));
    }
#pragma unroll
    for (int mt = 0; mt < 4; ++mt)
#pragma unroll
      for (int nt = 0; nt < 4; ++nt)
        acc[mt][nt] = MFMA_BF16(afr[mt], bfr[nt], acc[mt][nt]);
  }
}

// ---------------- K0: weight cast + BN constant folding ----------------
__global__ void k0_setup(const float* __restrict__ wq, const float* __restrict__ wk,
                         const float* __restrict__ wv, const float* __restrict__ wp,
                         const float* __restrict__ g1, const float* __restrict__ b1,
                         const float* __restrict__ m1, const float* __restrict__ v1,
                         const float* __restrict__ g2, const float* __restrict__ b2,
                         const float* __restrict__ m2, const float* __restrict__ v2,
                         __bf16* __restrict__ wqb, __bf16* __restrict__ wkb,
                         __bf16* __restrict__ wvb, __bf16* __restrict__ wpb,
                         float* __restrict__ s1o, float* __restrict__ b1o,
                         float* __restrict__ s2o, float* __restrict__ b2o)
{
  int i = blockIdx.x * 256 + threadIdx.x;
  wqb[i] = (__bf16)wq[i];
  wkb[i] = (__bf16)wk[i];
  wvb[i] = (__bf16)wv[i];
  wpb[i] = (__bf16)wp[i];
  if (blockIdx.x == 0) {
    int c = threadIdx.x;
    float s1 = g1[c] / sqrtf(v1[c] + 1e-5f);
    s1o[c] = s1;
    b1o[c] = b1[c] - m1[c] * s1;
    float s2 = g2[c] / sqrtf(v2[c] + 1e-5f);
    s2o[c] = s2;
    b2o[c] = b2[c] - m2[c] * s2;
  }
}

// ---------------- K1: per-window fused QKV projection + attention + blend ----------------
// Writes x (fp32) to the output buffer (it is the residual base; k4 accumulates onto it).
__global__ __launch_bounds__(256, 1) void k1_attn(
    const float* __restrict__ xe, const float* __restrict__ xv,
    const __bf16* __restrict__ wqb, const __bf16* __restrict__ wkb,
    const __bf16* __restrict__ wvb,
    const float* __restrict__ bn1s, const float* __restrict__ bn1b,
    float* __restrict__ xout)
{
  // ldsA: xe tile [p][c] -> later k [p][o]
  // ldsB: xv tile [p][c] -> later v [o][p] (channel-major, 128B rows)
  // ldsC: fused(bn1) tile [p][c] (kept for blend)
  // ldsD: q [p][o] -> later P (per-head column band)
  __shared__ __bf16 ldsA[16384];
  __shared__ __bf16 ldsB[16384];
  __shared__ __bf16 ldsC[16384];
  __shared__ __bf16 ldsD[16384];

  const int t = threadIdx.x;
  const int n = blockIdx.x;
  const int b = n >> 8, wh = (n >> 4) & 15, ww = n & 15;
  const int y0 = wh * 7, x0 = ww * 7;

  // zero the padding rows p=49..63 of the three input tiles (swizzle is a
  // within-row bijection, so zeroing unswizzled offsets zeroes everything)
  for (int idx = t; idx < 15 * 256; idx += 256) {
    int row = 49 + (idx >> 8);
    int cx = idx & 255;
    int off = row * 512 + cx * 2;
    *(__bf16*)((char*)ldsA + off) = (__bf16)0.f;
    *(__bf16*)((char*)ldsB + off) = (__bf16)0.f;
    *(__bf16*)((char*)ldsC + off) = (__bf16)0.f;
  }

  {
    const int lane8 = t & 7, cblk = t >> 3;
    for (int cc = 0; cc < 8; ++cc) {
      int c = cc * 32 + cblk;
      float sc = bn1s[c], bi = bn1b[c];
      const float* re = xe + ((b * 256 + c) * 112 + y0) * 112 + x0;
      const float* rv = xv + ((b * 256 + c) * 112 + y0) * 112 + x0;
      if (lane8 < 7) {
#pragma unroll
        for (int y = 0; y < 7; ++y) {
          float e = re[y * 112 + lane8];
          float v = rv[y * 112 + lane8];
          float f = (e + v) * sc + bi;
          int p = y * 7 + lane8;
          int off = p * 512 + ((c * 2) ^ ((p & 7) << 4));
          *(__bf16*)((char*)ldsA + off) = (__bf16)e;
          *(__bf16*)((char*)ldsB + off) = (__bf16)v;
          *(__bf16*)((char*)ldsC + off) = (__bf16)f;
        }
      }
    }
  }
  __syncthreads();

  const int w = t >> 6;
  const int l = t & 63;
  const int lm = l & 15, lg = l >> 4;

  // ---- Q projection (reads all ldsA, writes wave-private column band of ldsD) ----
  {
    f32x4 acc[4][4] = {};
    proj_mfma(wqb, ldsA, acc, w, lm, lg);
#pragma unroll
    for (int mt = 0; mt < 4; ++mt)
#pragma unroll
      for (int nt = 0; nt < 4; ++nt)
#pragma unroll
        for (int r = 0; r < 4; ++r) {
          int o = w * 64 + mt * 16 + lg * 4 + r;
          int p = nt * 16 + lm;
          int off = p * 512 + ((o * 2) ^ ((p & 7) << 4));
          *(__bf16*)((char*)ldsD + off) = (__bf16)acc[mt][nt][r];
        }
  }
  __syncthreads();  // all q reads of ldsA done before k overwrites it

  // ---- K projection (reads all ldsB, writes band of ldsA, position-major) ----
  {
    f32x4 acc[4][4] = {};
    proj_mfma(wkb, ldsB, acc, w, lm, lg);
#pragma unroll
    for (int mt = 0; mt < 4; ++mt)
#pragma unroll
      for (int nt = 0; nt < 4; ++nt)
#pragma unroll
        for (int r = 0; r < 4; ++r) {
          int o = w * 64 + mt * 16 + lg * 4 + r;
          int p = nt * 16 + lm;
          int off = p * 512 + ((o * 2) ^ ((p & 7) << 4));
          *(__bf16*)((char*)ldsA + off) = (__bf16)acc[mt][nt][r];
        }
  }
  __syncthreads();  // all k reads of ldsB done before v overwrites it

  // ---- V projection + relu (reads all ldsC, writes band of ldsB, channel-major) ----
  {
    f32x4 acc[4][4] = {};
    proj_mfma(wvb, ldsC, acc, w, lm, lg);
#pragma unroll
    for (int mt = 0; mt < 4; ++mt)
#pragma unroll
      for (int nt = 0; nt < 4; ++nt)
#pragma unroll
        for (int r = 0; r < 4; ++r) {
          int o = w * 64 + mt * 16 + lg * 4 + r;
          int p = nt * 16 + lm;
          float val = fmaxf(acc[mt][nt][r], 0.f);
          int off = o * 128 + ((p * 2) ^ ((o & 7) << 4));
          *(__bf16*)((char*)ldsB + off) = (__bf16)val;
        }
  }
  COMPILER_FENCE();
  __syncthreads();

  const int h = w;

  // ---- S = (q k^T) * 1/8 ----
  f32x4 sacc[4][4] = {};
  for (int ks = 0; ks < 2; ++ks) {
    bf16x8 aq[4], bk[4];
#pragma unroll
    for (int mt = 0; mt < 4; ++mt) {
      int qp = mt * 16 + lm;
      aq[mt] = ld_s16(ldsD, qp * 512 + (((h * 64 + ks * 32 + lg * 8) * 2) ^ ((qp & 7) << 4)));
    }
#pragma unroll
    for (int nt = 0; nt < 4; ++nt) {
      int kp = nt * 16 + lm;
      bk[nt] = ld_s16(ldsA, kp * 512 + (((h * 64 + ks * 32 + lg * 8) * 2) ^ ((kp & 7) << 4)));
    }
#pragma unroll
    for (int mt = 0; mt < 4; ++mt)
#pragma unroll
      for (int nt = 0; nt < 4; ++nt)
        sacc[mt][nt] = MFMA_BF16(aq[mt], bk[nt], sacc[mt][nt]);
  }

  // ---- softmax over kpos (49 real cols; padding cols are exact 0 -> masked) ----
  // D layout: lane holds col kp = nt*16 + lm, row qp = mt*16 + lg*4 + r.
#pragma unroll
  for (int mt = 0; mt < 4; ++mt) {
#pragma unroll
    for (int r = 0; r < 4; ++r) {
      float v0 = sacc[mt][0][r] * 0.125f;
      float v1 = sacc[mt][1][r] * 0.125f;
      float v2 = sacc[mt][2][r] * 0.125f;
      float v3 = sacc[mt][3][r] * 0.125f;
      float mx = fmaxf(fmaxf(v0, v1), fmaxf(v2, v3));
      mx = fmaxf(mx, __shfl_xor(mx, 1));
      mx = fmaxf(mx, __shfl_xor(mx, 2));
      mx = fmaxf(mx, __shfl_xor(mx, 4));
      mx = fmaxf(mx, __shfl_xor(mx, 8));
      float e0 = __expf(v0 - mx);
      float e1 = __expf(v1 - mx);
      float e2 = __expf(v2 - mx);
      float e3 = (lm == 0) ? __expf(v3 - mx) : 0.f;  // kp = 48+lm >= 49 masked
      float sum = e0 + e1 + e2 + e3;
      sum += __shfl_xor(sum, 1);
      sum += __shfl_xor(sum, 2);
      sum += __shfl_xor(sum, 4);
      sum += __shfl_xor(sum, 8);
      float inv = 1.f / sum;
      int qp = mt * 16 + lg * 4 + r;
      int base = qp * 512;
      int sw = (qp & 7) << 4;
      *(__bf16*)((char*)ldsD + base + (((h * 64 + 0  + lm) * 2) ^ sw)) = (__bf16)(e0 * inv);
      *(__bf16*)((char*)ldsD + base + (((h * 64 + 16 + lm) * 2) ^ sw)) = (__bf16)(e1 * inv);
      *(__bf16*)((char*)ldsD + base + (((h * 64 + 32 + lm) * 2) ^ sw)) = (__bf16)(e2 * inv);
      *(__bf16*)((char*)ldsD + base + (((h * 64 + 48 + lm) * 2) ^ sw)) = (__bf16)(e3 * inv);
    }
  }
  COMPILER_FENCE();

  // ---- x_sp = P @ v ----
  f32x4 oacc[4][4] = {};
  for (int ks = 0; ks < 2; ++ks) {
    bf16x8 ap[4], bv[4];
#pragma unroll
    for (int mt = 0; mt < 4; ++mt) {
      int qp = mt * 16 + lm;
      ap[mt] = ld_s16(ldsD, qp * 512 + (((h * 64 + ks * 32 + lg * 8) * 2) ^ ((qp & 7) << 4)));
    }
#pragma unroll
    for (int nt = 0; nt < 4; ++nt) {
      int o = h * 64 + nt * 16 + lm;  // v channel row (channel-major [o][kpos])
      bv[nt] = ld_s16(ldsB, o * 128 + (((ks * 32 + lg * 8) * 2) ^ ((o & 7) << 4)));
    }
#pragma unroll
    for (int mt = 0; mt < 4; ++mt)
#pragma unroll
      for (int nt = 0; nt < 4; ++nt)
        oacc[mt][nt] = MFMA_BF16(ap[mt], bv[nt], oacc[mt][nt]);
  }

  // ---- blend with constant imp, store x as FP32 ----
  const float IMP = (1.0f / 49.0f) / ((1.0f / 49.0f) + 1e-6f);
#pragma unroll
  for (int mt = 0; mt < 4; ++mt)
#pragma unroll
    for (int nt = 0; nt < 4; ++nt)
#pragma unroll
      for (int r = 0; r < 4; ++r) {
        int qp = mt * 16 + lg * 4 + r;
        if (qp < 49) {
          int c = h * 64 + nt * 16 + lm;
          float vwv = (float)*(const __bf16*)((const char*)ldsC +
                        qp * 512 + ((c * 2) ^ ((qp & 7) << 4)));
          float xval = IMP * oacc[mt][nt][r] + (1.f - IMP) * vwv;
          int yy = y0 + qp / 7;
          int xx = x0 + qp % 7;
          xout[((b * 256 + c) * 112 + yy) * 112 + xx] = xval;
        }
      }
}

// ---------------- K2: depthwise 3x3 + BN2 + SiLU + pool partial ----------------
// Reads x (fp32) from the output buffer; writes y1 (bf16) into workspace.
__global__ __launch_bounds__(256) void k2_conv(
    const float* __restrict__ xin, const float* __restrict__ dww,
    const float* __restrict__ bn2s, const float* __restrict__ bn2b,
    __bf16* __restrict__ y1, float* __restrict__ pm)
{
  const int bc = blockIdx.x;
  const int c = bc & 255;
  const float* plane = xin + bc * 12544;
  float wgt[9];
#pragma unroll
  for (int i = 0; i < 9; ++i) wgt[i] = dww[c * 9 + i];
  const float sc = bn2s[c], bi = bn2b[c];
  const int t = threadIdx.x;
  float lsum = 0.f;
  for (int i = 0; i < 49; ++i) {
    int p = t + (i << 8);
    int y = p / 112;
    int x = p - y * 112;
    float acc = 0.f;
#pragma unroll
    for (int dy = -1; dy <= 1; ++dy) {
      int yy = y + dy;
      if (yy < 0 || yy > 111) continue;
#pragma unroll
      for (int dx = -1; dx <= 1; ++dx) {
        int xx = x + dx;
        if (xx < 0 || xx > 111) continue;
        acc += plane[yy * 112 + xx] * wgt[(dy + 1) * 3 + (dx + 1)];
      }
    }
    float u = acc * sc + bi;
    float sl = u / (1.f + __expf(-u));
    y1[bc * 12544 + p] = (__bf16)sl;
    lsum += sl;
  }
  lsum += __shfl_xor(lsum, 1);
  lsum += __shfl_xor(lsum, 2);
  lsum += __shfl_xor(lsum, 4);
  lsum += __shfl_xor(lsum, 8);
  lsum += __shfl_xor(lsum, 16);
  lsum += __shfl_xor(lsum, 32);
  __shared__ float red[4];
  if ((t & 63) == 0) red[t >> 6] = lsum;
  __syncthreads();
  if (t == 0) pm[bc] = (red[0] + red[1] + red[2] + red[3]) * (1.0f / 12544.0f);
}

// ---------------- K3: ECA gate ----------------
__global__ void k3_eca(const float* __restrict__ pm, const float* __restrict__ ecaw,
                       float* __restrict__ gate)
{
  int b = blockIdx.x, c = threadIdx.x;
  float p0 = (c > 0) ? pm[b * 256 + c - 1] : 0.f;
  float p1 = pm[b * 256 + c];
  float p2 = (c < 255) ? pm[b * 256 + c + 1] : 0.f;
  float a = ecaw[0] * p0 + ecaw[1] * p1 + ecaw[2] * p2;
  gate[b * 256 + c] = 1.f / (1.f + __expf(-a));
}

// ---------------- K4: out(fp32, in-place) = x + wp @ (y1 * gate) ----------------
__global__ __launch_bounds__(256) void k4_out(
    const __bf16* __restrict__ y1, const float* __restrict__ gate,
    const __bf16* __restrict__ wpb, float* out_inout)
{
  __shared__ __bf16 bt[16384];  // [64 pos][256 ch] bf16, swizzled
  const int t = threadIdx.x;
  const int blk = blockIdx.x;
  const int b = blk / 196;
  const int s0 = (blk - b * 196) * 64;
  const int chunk = t & 7, crow = t >> 3;
#pragma unroll
  for (int cc = 0; cc < 8; ++cc) {
    int c = cc * 32 + crow;
    float g = gate[b * 256 + c];
    const __bf16* src = y1 + (b * 256 + c) * 12544 + s0 + chunk * 8;
    bf16x8 v = *(const bf16x8*)src;
#pragma unroll
    for (int j = 0; j < 8; ++j) {
      int s = chunk * 8 + j;
      float f = (float)v[j] * g;
      *(__bf16*)((char*)bt + s * 512 + ((c * 2) ^ ((s & 7) << 4))) = (__bf16)f;
    }
  }
  __syncthreads();
  const int w = t >> 6, l = t & 63, lm = l & 15, lg = l >> 4;
  f32x4 acc[4][4] = {};
  proj_mfma(wpb, bt, acc, w, lm, lg);
#pragma unroll
  for (int mt = 0; mt < 4; ++mt)
#pragma unroll
    for (int nt = 0; nt < 4; ++nt)
#pragma unroll
      for (int r = 0; r < 4; ++r) {
        int o = w * 64 + mt * 16 + lg * 4 + r;
        int s = nt * 16 + lm;
        int idx = (b * 256 + o) * 12544 + s0 + s;
        out_inout[idx] = out_inout[idx] + acc[mt][nt][r];
      }
}

// ---------------- launcher ----------------
extern "C" void kernel_launch(void* const* d_in, const int* in_sizes, int n_in,
                              void* d_out, int out_size, void* d_ws, size_t ws_size,
                              hipStream_t stream) {
  const float* x_edge = (const float*)d_in[0];
  const float* x_vit  = (const float*)d_in[1];
  const float* bn1_g  = (const float*)d_in[2];
  const float* bn1_b  = (const float*)d_in[3];
  const float* bn1_m  = (const float*)d_in[4];
  const float* bn1_v  = (const float*)d_in[5];
  const float* wq     = (const float*)d_in[6];
  const float* wk     = (const float*)d_in[7];
  const float* wv     = (const float*)d_in[8];
  const float* dw_w   = (const float*)d_in[9];
  const float* bn2_g  = (const float*)d_in[10];
  const float* bn2_b  = (const float*)d_in[11];
  const float* bn2_m  = (const float*)d_in[12];
  const float* bn2_v  = (const float*)d_in[13];
  const float* eca_w  = (const float*)d_in[14];
  const float* wp     = (const float*)d_in[15];

  float* out = (float*)d_out;  // reference output dtype is float32

  char* ws = (char*)d_ws;
  __bf16* y1 = (__bf16*)ws;                        // 16*256*112*112 bf16 = 102,760,448 B
  const size_t o1 = 102760448;
  __bf16* wqb  = (__bf16*)(ws + o1);
  __bf16* wkb  = (__bf16*)(ws + o1 + 131072);
  __bf16* wvb  = (__bf16*)(ws + o1 + 262144);
  __bf16* wpb  = (__bf16*)(ws + o1 + 393216);
  float*  bn1s = (float*)(ws + o1 + 524288);
  float*  bn1bb= (float*)(ws + o1 + 525312);
  float*  bn2s = (float*)(ws + o1 + 526336);
  float*  bn2bb= (float*)(ws + o1 + 527360);
  float*  pm   = (float*)(ws + o1 + 528384);
  float*  gate = (float*)(ws + o1 + 544768);

  hipLaunchKernelGGL(k0_setup, dim3(256), dim3(256), 0, stream,
                     wq, wk, wv, wp, bn1_g, bn1_b, bn1_m, bn1_v,
                     bn2_g, bn2_b, bn2_m, bn2_v,
                     wqb, wkb, wvb, wpb, bn1s, bn1bb, bn2s, bn2bb);
  hipLaunchKernelGGL(k1_attn, dim3(4096), dim3(256), 0, stream,
                     x_edge, x_vit, wqb, wkb, wvb, bn1s, bn1bb, out);
  hipLaunchKernelGGL(k2_conv, dim3(4096), dim3(256), 0, stream,
                     out, dw_w, bn2s, bn2bb, y1, pm);
  hipLaunchKernelGGL(k3_eca, dim3(16), dim3(256), 0, stream, pm, eca_w, gate);
  hipLaunchKernelGGL(k4_out, dim3(3136), dim3(256), 0, stream,
                     y1, gate, wpb, out);
}

// Round 4
// 1188.195 us; speedup vs baseline: 1.1482x; 1.1482x over previous
//
#include <hip/hip_runtime.h>

typedef unsigned short u16;
typedef __bf16 bf16x4 __attribute__((ext_vector_type(4)));
typedef __bf16 bf16x8 __attribute__((ext_vector_type(8)));
typedef float f32x4 __attribute__((ext_vector_type(4)));

#define MFMA_BF16(a, b, c) __builtin_amdgcn_mfma_f32_16x16x32_bf16((a), (b), (c), 0, 0, 0)
#define COMPILER_FENCE() asm volatile("" ::: "memory")

__device__ __forceinline__ bf16x8 ld_g16(const __bf16* p) {
  return *(const bf16x8*)p;
}
__device__ __forceinline__ bf16x8 ld_s16(const __bf16* base, int byteoff) {
  return *(const bf16x8*)((const char*)base + byteoff);
}

// OUT[o][p] = sum_c W[o][c] * SRC[c][p] for TWO weight matrices sharing B-frags.
// SRC in LDS position-major [p][c] bf16, rows 512B, XOR-swizzled by ((p&7)<<4).
__device__ __forceinline__ void proj2_mfma(const __bf16* __restrict__ W0,
                                           const __bf16* __restrict__ W1,
                                           const __bf16* src,
                                           f32x4 (&a0)[4][4], f32x4 (&a1)[4][4],
                                           int w, int lm, int lg)
{
  for (int ks = 0; ks < 8; ++ks) {
    bf16x8 f0[4], f1[4], bfr[4];
#pragma unroll
    for (int mt = 0; mt < 4; ++mt) {
      int row = (w * 64 + mt * 16 + lm) * 256 + ks * 32 + lg * 8;
      f0[mt] = ld_g16(W0 + row);
      f1[mt] = ld_g16(W1 + row);
    }
#pragma unroll
    for (int nt = 0; nt < 4; ++nt) {
      int p = nt * 16 + lm;
      bfr[nt] = ld_s16(src, p * 512 + (((ks * 32 + lg * 8) * 2) ^ ((p & 7) << 4)));
    }
#pragma unroll
    for (int mt = 0; mt < 4; ++mt)
#pragma unroll
      for (int nt = 0; nt < 4; ++nt) {
        a0[mt][nt] = MFMA_BF16(f0[mt], bfr[nt], a0[mt][nt]);
        a1[mt][nt] = MFMA_BF16(f1[mt], bfr[nt], a1[mt][nt]);
      }
  }
}

// Single-weight variant (for k4).
__device__ __forceinline__ void proj_mfma(const __bf16* __restrict__ Wg,
                                          const __bf16* src, f32x4 (&acc)[4][4],
                                          int w, int lm, int lg)
{
  for (int ks = 0; ks < 8; ++ks) {
    bf16x8 afr[4], bfr[4];
#pragma unroll
    for (int mt = 0; mt < 4; ++mt)
      afr[mt] = ld_g16(Wg + (w * 64 + mt * 16 + lm) * 256 + ks * 32 + lg * 8);
#pragma unroll
    for (int nt = 0; nt < 4; ++nt) {
      int p = nt * 16 + lm;
      bfr[nt] = ld_s16(src, p * 512 + (((ks * 32 + lg * 8) * 2) ^ ((p & 7) << 4)));
    }
#pragma unroll
    for (int mt = 0; mt < 4; ++mt)
#pragma unroll
      for (int nt = 0; nt < 4; ++nt)
        acc[mt][nt] = MFMA_BF16(afr[mt], bfr[nt], acc[mt][nt]);
  }
}

// Store acc as bf16 into [p][o] swizzled layout, 4 consecutive o (r-dim) packed per b64.
__device__ __forceinline__ void store_pkband(__bf16* buf, const f32x4 (&acc)[4][4],
                                             int w, int lm, int lg)
{
#pragma unroll
  for (int mt = 0; mt < 4; ++mt)
#pragma unroll
    for (int nt = 0; nt < 4; ++nt) {
      int o0 = w * 64 + mt * 16 + lg * 4;
      int p = nt * 16 + lm;
      bf16x4 v4;
#pragma unroll
      for (int r = 0; r < 4; ++r) v4[r] = (__bf16)acc[mt][nt][r];
      *(bf16x4*)((char*)buf + p * 512 + ((o0 * 2) ^ ((p & 7) << 4))) = v4;
    }
}

// ---------------- K0: weight cast + BN folding (bn1 folded into wv' and beta_v) -------
__global__ void k0_setup(const float* __restrict__ wq, const float* __restrict__ wk,
                         const float* __restrict__ wv, const float* __restrict__ wp,
                         const float* __restrict__ g1, const float* __restrict__ b1,
                         const float* __restrict__ m1, const float* __restrict__ v1,
                         const float* __restrict__ g2, const float* __restrict__ b2,
                         const float* __restrict__ m2, const float* __restrict__ v2,
                         __bf16* __restrict__ wqb, __bf16* __restrict__ wkb,
                         __bf16* __restrict__ wvb, __bf16* __restrict__ wpb,
                         float* __restrict__ betav,
                         float* __restrict__ s2o, float* __restrict__ b2o)
{
  int i = blockIdx.x * 256 + threadIdx.x;
  int c = i & 255;
  float s1 = g1[c] * rsqrtf(v1[c] + 1e-5f);
  wqb[i] = (__bf16)wq[i];
  wkb[i] = (__bf16)wk[i];
  wvb[i] = (__bf16)(wv[i] * s1);   // wv' = wv * s1[c]
  wpb[i] = (__bf16)wp[i];
  if (blockIdx.x == 0) {
    int o = threadIdx.x;
    float acc = 0.f;
    for (int cc = 0; cc < 256; ++cc) {
      float s1c = g1[cc] * rsqrtf(v1[cc] + 1e-5f);
      float b1f = b1[cc] - m1[cc] * s1c;
      acc += wv[o * 256 + cc] * b1f;
    }
    betav[o] = acc;                 // beta_v[o] = wv[o,:] @ b1_folded
    float s2 = g2[o] * rsqrtf(v2[o] + 1e-5f);
    s2o[o] = s2;
    b2o[o] = b2[o] - m2[o] * s2;
  }
}

// ---------------- K1: per-window fused QKV projection + attention ----------------
// 64 KiB LDS -> 2 blocks/CU. Writes x = IMP * x_sp (fp32) into the output buffer.
// (1-IMP)*fused term dropped: (1-IMP)=4.88e-5, |fused|<~8 -> error <4e-4, far below tol.
__global__ __launch_bounds__(256, 2) void k1_attn(
    const float* __restrict__ xe, const float* __restrict__ xv,
    const __bf16* __restrict__ wqb, const __bf16* __restrict__ wkb,
    const __bf16* __restrict__ wvb, const float* __restrict__ betav,
    float* __restrict__ xout)
{
  // B0: xe tile [p][c] -> q [p][o] -> P (own head band)
  // B1: xv tile [p][c] -> k [p][o] -> v (own head band, [o_local][kp] rows 512B @ +128h)
  __shared__ __bf16 B0[16384];
  __shared__ __bf16 B1[16384];

  const int t = threadIdx.x;
  const int n = blockIdx.x;
  const int b = n >> 8, wh = (n >> 4) & 15, ww = n & 15;
  const int y0 = wh * 7, x0 = ww * 7;

  // zero padding rows p=49..63
  for (int idx = t; idx < 15 * 256; idx += 256) {
    int off = (49 + (idx >> 8)) * 512 + (idx & 255) * 2;
    *(__bf16*)((char*)B0 + off) = (__bf16)0.f;
    *(__bf16*)((char*)B1 + off) = (__bf16)0.f;
  }

  {
    const int lane8 = t & 7, cblk = t >> 3;
    if (lane8 < 7) {
      for (int cc = 0; cc < 8; ++cc) {
        int c = cc * 32 + cblk;
        const float* re = xe + ((b * 256 + c) * 112 + y0) * 112 + x0;
        const float* rv = xv + ((b * 256 + c) * 112 + y0) * 112 + x0;
#pragma unroll
        for (int y = 0; y < 7; ++y) {
          float e = re[y * 112 + lane8];
          float v = rv[y * 112 + lane8];
          int p = y * 7 + lane8;
          int off = p * 512 + ((c * 2) ^ ((p & 7) << 4));
          *(__bf16*)((char*)B0 + off) = (__bf16)e;
          *(__bf16*)((char*)B1 + off) = (__bf16)v;
        }
      }
    }
  }
  __syncthreads();

  const int w = t >> 6;
  const int l = t & 63;
  const int lm = l & 15, lg = l >> 4;
  const int h = w;

  // ---- pass 1 over B0 (xe): Vacc = wv'@xe, Qacc = wq@xe ----
  f32x4 vac[4][4] = {};
  {
    f32x4 qac[4][4] = {};
    proj2_mfma(wvb, wqb, B0, vac, qac, w, lm, lg);
    __syncthreads();               // all waves done reading B0
    store_pkband(B0, qac, w, lm, lg);   // q -> B0 (own band)
    COMPILER_FENCE();
  }

  // ---- pass 2 over B1 (xv): Vacc += wv'@xv, Kacc = wk@xv ----
  {
    f32x4 kac[4][4] = {};
    proj2_mfma(wvb, wkb, B1, vac, kac, w, lm, lg);
    __syncthreads();               // all waves done reading B1
    store_pkband(B1, kac, w, lm, lg);   // k -> B1 (own band)
    COMPILER_FENCE();
  }

  // ---- S = (q k^T) * 1/8 (reads own head bands of B0=q, B1=k; wave-private) ----
  f32x4 sacc[4][4] = {};
  for (int ks = 0; ks < 2; ++ks) {
    bf16x8 aq[4], bk[4];
#pragma unroll
    for (int mt = 0; mt < 4; ++mt) {
      int qp = mt * 16 + lm;
      aq[mt] = ld_s16(B0, qp * 512 + (((h * 64 + ks * 32 + lg * 8) * 2) ^ ((qp & 7) << 4)));
    }
#pragma unroll
    for (int nt = 0; nt < 4; ++nt) {
      int kp = nt * 16 + lm;
      bk[nt] = ld_s16(B1, kp * 512 + (((h * 64 + ks * 32 + lg * 8) * 2) ^ ((kp & 7) << 4)));
    }
#pragma unroll
    for (int mt = 0; mt < 4; ++mt)
#pragma unroll
      for (int nt = 0; nt < 4; ++nt)
        sacc[mt][nt] = MFMA_BF16(aq[mt], bk[nt], sacc[mt][nt]);
  }

  // ---- softmax over kpos (padding cols exact 0 in S -> masked) ----
#pragma unroll
  for (int mt = 0; mt < 4; ++mt) {
#pragma unroll
    for (int r = 0; r < 4; ++r) {
      float v0 = sacc[mt][0][r] * 0.125f;
      float v1 = sacc[mt][1][r] * 0.125f;
      float v2 = sacc[mt][2][r] * 0.125f;
      float v3 = sacc[mt][3][r] * 0.125f;
      float mx = fmaxf(fmaxf(v0, v1), fmaxf(v2, v3));
      mx = fmaxf(mx, __shfl_xor(mx, 1));
      mx = fmaxf(mx, __shfl_xor(mx, 2));
      mx = fmaxf(mx, __shfl_xor(mx, 4));
      mx = fmaxf(mx, __shfl_xor(mx, 8));
      float e0 = __expf(v0 - mx);
      float e1 = __expf(v1 - mx);
      float e2 = __expf(v2 - mx);
      float e3 = (lm == 0) ? __expf(v3 - mx) : 0.f;  // kp = 48+lm >= 49 masked
      float sum = e0 + e1 + e2 + e3;
      sum += __shfl_xor(sum, 1);
      sum += __shfl_xor(sum, 2);
      sum += __shfl_xor(sum, 4);
      sum += __shfl_xor(sum, 8);
      float inv = 1.f / sum;
      int qp = mt * 16 + lg * 4 + r;
      int base = qp * 512;
      int sw = (qp & 7) << 4;
      *(__bf16*)((char*)B0 + base + (((h * 64 + 0  + lm) * 2) ^ sw)) = (__bf16)(e0 * inv);
      *(__bf16*)((char*)B0 + base + (((h * 64 + 16 + lm) * 2) ^ sw)) = (__bf16)(e1 * inv);
      *(__bf16*)((char*)B0 + base + (((h * 64 + 32 + lm) * 2) ^ sw)) = (__bf16)(e2 * inv);
      *(__bf16*)((char*)B0 + base + (((h * 64 + 48 + lm) * 2) ^ sw)) = (__bf16)(e3 * inv);
    }
  }
  COMPILER_FENCE();

  // ---- finalize v = relu(Vacc + beta), store into own band of B1: [o_local][kp] ----
  {
    float beta[4][4];
#pragma unroll
    for (int mt = 0; mt < 4; ++mt) {
      f32x4 bv = *(const f32x4*)(betav + w * 64 + mt * 16 + lg * 4);
#pragma unroll
      for (int r = 0; r < 4; ++r) beta[mt][r] = bv[r];
    }
#pragma unroll
    for (int mt = 0; mt < 4; ++mt)
#pragma unroll
      for (int nt = 0; nt < 4; ++nt)
#pragma unroll
        for (int r = 0; r < 4; ++r) {
          int ol = mt * 16 + lg * 4 + r;     // o_local within head
          int p = nt * 16 + lm;              // kp (padded kp never used: P=0 there)
          float val = fmaxf(vac[mt][nt][r] + beta[mt][r], 0.f);
          int off = ol * 512 + h * 128 + ((p * 2) ^ ((ol & 7) << 4));
          *(__bf16*)((char*)B1 + off) = (__bf16)val;
        }
  }
  COMPILER_FENCE();

  // ---- x_sp = P @ v ----
  f32x4 oacc[4][4] = {};
  for (int ks = 0; ks < 2; ++ks) {
    bf16x8 ap[4], bv[4];
#pragma unroll
    for (int mt = 0; mt < 4; ++mt) {
      int qp = mt * 16 + lm;
      ap[mt] = ld_s16(B0, qp * 512 + (((h * 64 + ks * 32 + lg * 8) * 2) ^ ((qp & 7) << 4)));
    }
#pragma unroll
    for (int nt = 0; nt < 4; ++nt) {
      int ol = nt * 16 + lm;
      bv[nt] = ld_s16(B1, ol * 512 + h * 128 + (((ks * 32 + lg * 8) * 2) ^ ((ol & 7) << 4)));
    }
#pragma unroll
    for (int mt = 0; mt < 4; ++mt)
#pragma unroll
      for (int nt = 0; nt < 4; ++nt)
        oacc[mt][nt] = MFMA_BF16(ap[mt], bv[nt], oacc[mt][nt]);
  }

  // ---- store x = IMP * x_sp (fp32) ----
  const float IMP = (1.0f / 49.0f) / ((1.0f / 49.0f) + 1e-6f);
#pragma unroll
  for (int mt = 0; mt < 4; ++mt)
#pragma unroll
    for (int nt = 0; nt < 4; ++nt)
#pragma unroll
      for (int r = 0; r < 4; ++r) {
        int qp = mt * 16 + lg * 4 + r;
        if (qp < 49) {
          int c = h * 64 + nt * 16 + lm;
          int yy = y0 + qp / 7;
          int xx = x0 + qp % 7;
          xout[((b * 256 + c) * 112 + yy) * 112 + xx] = IMP * oacc[mt][nt][r];
        }
      }
}

// ---------------- K2: depthwise 3x3 + BN2 + SiLU + pool partial ----------------
__global__ __launch_bounds__(256) void k2_conv(
    const float* __restrict__ xin, const float* __restrict__ dww,
    const float* __restrict__ bn2s, const float* __restrict__ bn2b,
    __bf16* __restrict__ y1, float* __restrict__ pm)
{
  const int bc = blockIdx.x;
  const int c = bc & 255;
  const float* plane = xin + bc * 12544;
  float wgt[9];
#pragma unroll
  for (int i = 0; i < 9; ++i) wgt[i] = dww[c * 9 + i];
  const float sc = bn2s[c], bi = bn2b[c];
  const int t = threadIdx.x;
  float lsum = 0.f;
  for (int i = 0; i < 49; ++i) {
    int p = t + (i << 8);
    int y = p / 112;
    int x = p - y * 112;
    float acc = 0.f;
#pragma unroll
    for (int dy = -1; dy <= 1; ++dy) {
      int yy = y + dy;
      if (yy < 0 || yy > 111) continue;
#pragma unroll
      for (int dx = -1; dx <= 1; ++dx) {
        int xx = x + dx;
        if (xx < 0 || xx > 111) continue;
        acc += plane[yy * 112 + xx] * wgt[(dy + 1) * 3 + (dx + 1)];
      }
    }
    float u = acc * sc + bi;
    float sl = u / (1.f + __expf(-u));
    y1[bc * 12544 + p] = (__bf16)sl;
    lsum += sl;
  }
  lsum += __shfl_xor(lsum, 1);
  lsum += __shfl_xor(lsum, 2);
  lsum += __shfl_xor(lsum, 4);
  lsum += __shfl_xor(lsum, 8);
  lsum += __shfl_xor(lsum, 16);
  lsum += __shfl_xor(lsum, 32);
  __shared__ float red[4];
  if ((t & 63) == 0) red[t >> 6] = lsum;
  __syncthreads();
  if (t == 0) pm[bc] = (red[0] + red[1] + red[2] + red[3]) * (1.0f / 12544.0f);
}

// ---------------- K3: ECA gate ----------------
__global__ void k3_eca(const float* __restrict__ pm, const float* __restrict__ ecaw,
                       float* __restrict__ gate)
{
  int b = blockIdx.x, c = threadIdx.x;
  float p0 = (c > 0) ? pm[b * 256 + c - 1] : 0.f;
  float p1 = pm[b * 256 + c];
  float p2 = (c < 255) ? pm[b * 256 + c + 1] : 0.f;
  float a = ecaw[0] * p0 + ecaw[1] * p1 + ecaw[2] * p2;
  gate[b * 256 + c] = 1.f / (1.f + __expf(-a));
}

// ---------------- K4: out(fp32, in-place) = x + wp @ (y1 * gate) ----------------
__global__ __launch_bounds__(256) void k4_out(
    const __bf16* __restrict__ y1, const float* __restrict__ gate,
    const __bf16* __restrict__ wpb, float* out_inout)
{
  __shared__ __bf16 bt[16384];  // [64 pos][256 ch] bf16, swizzled
  const int t = threadIdx.x;
  const int blk = blockIdx.x;
  const int b = blk / 196;
  const int s0 = (blk - b * 196) * 64;
  const int chunk = t & 7, crow = t >> 3;
#pragma unroll
  for (int cc = 0; cc < 8; ++cc) {
    int c = cc * 32 + crow;
    float g = gate[b * 256 + c];
    const __bf16* src = y1 + (b * 256 + c) * 12544 + s0 + chunk * 8;
    bf16x8 v = *(const bf16x8*)src;
#pragma unroll
    for (int j = 0; j < 8; ++j) {
      int s = chunk * 8 + j;
      float f = (float)v[j] * g;
      *(__bf16*)((char*)bt + s * 512 + ((c * 2) ^ ((s & 7) << 4))) = (__bf16)f;
    }
  }
  __syncthreads();
  const int w = t >> 6, l = t & 63, lm = l & 15, lg = l >> 4;
  f32x4 acc[4][4] = {};
  proj_mfma(wpb, bt, acc, w, lm, lg);
#pragma unroll
  for (int mt = 0; mt < 4; ++mt)
#pragma unroll
    for (int nt = 0; nt < 4; ++nt)
#pragma unroll
      for (int r = 0; r < 4; ++r) {
        int o = w * 64 + mt * 16 + lg * 4 + r;
        int s = nt * 16 + lm;
        int idx = (b * 256 + o) * 12544 + s0 + s;
        out_inout[idx] = out_inout[idx] + acc[mt][nt][r];
      }
}

// ---------------- launcher ----------------
extern "C" void kernel_launch(void* const* d_in, const int* in_sizes, int n_in,
                              void* d_out, int out_size, void* d_ws, size_t ws_size,
                              hipStream_t stream) {
  const float* x_edge = (const float*)d_in[0];
  const float* x_vit  = (const float*)d_in[1];
  const float* bn1_g  = (const float*)d_in[2];
  const float* bn1_b  = (const float*)d_in[3];
  const float* bn1_m  = (const float*)d_in[4];
  const float* bn1_v  = (const float*)d_in[5];
  const float* wq     = (const float*)d_in[6];
  const float* wk     = (const float*)d_in[7];
  const float* wv     = (const float*)d_in[8];
  const float* dw_w   = (const float*)d_in[9];
  const float* bn2_g  = (const float*)d_in[10];
  const float* bn2_b  = (const float*)d_in[11];
  const float* bn2_m  = (const float*)d_in[12];
  const float* bn2_v  = (const float*)d_in[13];
  const float* eca_w  = (const float*)d_in[14];
  const float* wp     = (const float*)d_in[15];

  float* out = (float*)d_out;  // reference output dtype is float32

  char* ws = (char*)d_ws;
  __bf16* y1 = (__bf16*)ws;                        // 16*256*112*112 bf16 = 102,760,448 B
  const size_t o1 = 102760448;
  __bf16* wqb  = (__bf16*)(ws + o1);
  __bf16* wkb  = (__bf16*)(ws + o1 + 131072);
  __bf16* wvb  = (__bf16*)(ws + o1 + 262144);
  __bf16* wpb  = (__bf16*)(ws + o1 + 393216);
  float*  betav= (float*)(ws + o1 + 524288);       // 1 KiB
  float*  bn2s = (float*)(ws + o1 + 525312);
  float*  bn2bb= (float*)(ws + o1 + 526336);
  float*  pm   = (float*)(ws + o1 + 527360);       // 16 KiB
  float*  gate = (float*)(ws + o1 + 543744);       // 16 KiB

  hipLaunchKernelGGL(k0_setup, dim3(256), dim3(256), 0, stream,
                     wq, wk, wv, wp, bn1_g, bn1_b, bn1_m, bn1_v,
                     bn2_g, bn2_b, bn2_m, bn2_v,
                     wqb, wkb, wvb, wpb, betav, bn2s, bn2bb);
  hipLaunchKernelGGL(k1_attn, dim3(4096), dim3(256), 0, stream,
                     x_edge, x_vit, wqb, wkb, wvb, betav, out);
  hipLaunchKernelGGL(k2_conv, dim3(4096), dim3(256), 0, stream,
                     out, dw_w, bn2s, bn2bb, y1, pm);
  hipLaunchKernelGGL(k3_eca, dim3(16), dim3(256), 0, stream, pm, eca_w, gate);
  hipLaunchKernelGGL(k4_out, dim3(3136), dim3(256), 0, stream,
                     y1, gate, wpb, out);
}

// Round 5
// 1039.154 us; speedup vs baseline: 1.3128x; 1.1434x over previous
//
#include <hip/hip_runtime.h>

typedef unsigned short u16;
typedef __bf16 bf16x4 __attribute__((ext_vector_type(4)));
typedef __bf16 bf16x8 __attribute__((ext_vector_type(8)));
typedef float f32x4 __attribute__((ext_vector_type(4)));

#define MFMA_BF16(a, b, c) __builtin_amdgcn_mfma_f32_16x16x32_bf16((a), (b), (c), 0, 0, 0)
#define COMPILER_FENCE() asm volatile("" ::: "memory")

__device__ __forceinline__ bf16x8 ld_g16(const __bf16* p) {
  return *(const bf16x8*)p;
}
__device__ __forceinline__ bf16x8 ld_s16(const __bf16* base, int byteoff) {
  return *(const bf16x8*)((const char*)base + byteoff);
}

// OUT[o][p] = sum_c W[o][c] * SRC[c][p] for TWO weight matrices sharing B-frags.
// SRC in LDS position-major [p][c] bf16, rows 512B, XOR-swizzled by ((p&7)<<4).
__device__ __forceinline__ void proj2_mfma(const __bf16* __restrict__ W0,
                                           const __bf16* __restrict__ W1,
                                           const __bf16* src,
                                           f32x4 (&a0)[4][4], f32x4 (&a1)[4][4],
                                           int w, int lm, int lg)
{
  for (int ks = 0; ks < 8; ++ks) {
    bf16x8 f0[4], f1[4], bfr[4];
#pragma unroll
    for (int mt = 0; mt < 4; ++mt) {
      int row = (w * 64 + mt * 16 + lm) * 256 + ks * 32 + lg * 8;
      f0[mt] = ld_g16(W0 + row);
      f1[mt] = ld_g16(W1 + row);
    }
#pragma unroll
    for (int nt = 0; nt < 4; ++nt) {
      int p = nt * 16 + lm;
      bfr[nt] = ld_s16(src, p * 512 + (((ks * 32 + lg * 8) * 2) ^ ((p & 7) << 4)));
    }
#pragma unroll
    for (int mt = 0; mt < 4; ++mt)
#pragma unroll
      for (int nt = 0; nt < 4; ++nt) {
        a0[mt][nt] = MFMA_BF16(f0[mt], bfr[nt], a0[mt][nt]);
        a1[mt][nt] = MFMA_BF16(f1[mt], bfr[nt], a1[mt][nt]);
      }
  }
}

// Single-weight variant (for k4).
__device__ __forceinline__ void proj_mfma(const __bf16* __restrict__ Wg,
                                          const __bf16* src, f32x4 (&acc)[4][4],
                                          int w, int lm, int lg)
{
  for (int ks = 0; ks < 8; ++ks) {
    bf16x8 afr[4], bfr[4];
#pragma unroll
    for (int mt = 0; mt < 4; ++mt)
      afr[mt] = ld_g16(Wg + (w * 64 + mt * 16 + lm) * 256 + ks * 32 + lg * 8);
#pragma unroll
    for (int nt = 0; nt < 4; ++nt) {
      int p = nt * 16 + lm;
      bfr[nt] = ld_s16(src, p * 512 + (((ks * 32 + lg * 8) * 2) ^ ((p & 7) << 4)));
    }
#pragma unroll
    for (int mt = 0; mt < 4; ++mt)
#pragma unroll
      for (int nt = 0; nt < 4; ++nt)
        acc[mt][nt] = MFMA_BF16(afr[mt], bfr[nt], acc[mt][nt]);
  }
}

// Store acc as bf16 into [p][o] swizzled layout, 4 consecutive o packed per b64.
__device__ __forceinline__ void store_pkband(__bf16* buf, const f32x4 (&acc)[4][4],
                                             int w, int lm, int lg)
{
#pragma unroll
  for (int mt = 0; mt < 4; ++mt)
#pragma unroll
    for (int nt = 0; nt < 4; ++nt) {
      int o0 = w * 64 + mt * 16 + lg * 4;
      int p = nt * 16 + lm;
      bf16x4 v4;
#pragma unroll
      for (int r = 0; r < 4; ++r) v4[r] = (__bf16)acc[mt][nt][r];
      *(bf16x4*)((char*)buf + p * 512 + ((o0 * 2) ^ ((p & 7) << 4))) = v4;
    }
}

// ---------------- K0: weight cast + BN folding + parallel betav ----------------
__global__ void k0_setup(const float* __restrict__ wq, const float* __restrict__ wk,
                         const float* __restrict__ wv, const float* __restrict__ wp,
                         const float* __restrict__ g1, const float* __restrict__ b1,
                         const float* __restrict__ m1, const float* __restrict__ v1,
                         const float* __restrict__ g2, const float* __restrict__ b2,
                         const float* __restrict__ m2, const float* __restrict__ v2,
                         __bf16* __restrict__ wqb, __bf16* __restrict__ wkb,
                         __bf16* __restrict__ wvb, __bf16* __restrict__ wpb,
                         float* __restrict__ betav,
                         float* __restrict__ s2o, float* __restrict__ b2o)
{
  const int t = threadIdx.x;
  const int i = blockIdx.x * 256 + t;   // i % 256 == t
  const int c = t;
  float s1 = g1[c] * rsqrtf(v1[c] + 1e-5f);
  wqb[i] = (__bf16)wq[i];
  wkb[i] = (__bf16)wk[i];
  wvb[i] = (__bf16)(wv[i] * s1);        // wv' = wv * s1[c]
  wpb[i] = (__bf16)wp[i];
  // betav[o] = wv[o,:] @ (b1 - m1*s1), o = blockIdx.x
  float contrib = wv[i] * (b1[c] - m1[c] * s1);
  contrib += __shfl_xor(contrib, 1);
  contrib += __shfl_xor(contrib, 2);
  contrib += __shfl_xor(contrib, 4);
  contrib += __shfl_xor(contrib, 8);
  contrib += __shfl_xor(contrib, 16);
  contrib += __shfl_xor(contrib, 32);
  __shared__ float rb[4];
  if ((t & 63) == 0) rb[t >> 6] = contrib;
  __syncthreads();
  if (t == 0) betav[blockIdx.x] = rb[0] + rb[1] + rb[2] + rb[3];
  if (blockIdx.x == 0) {
    float s2 = g2[t] * rsqrtf(v2[t] + 1e-5f);
    s2o[t] = s2;
    b2o[t] = b2[t] - m2[t] * s2;
  }
}

// ---------------- K_PRE: im2col transpose to swizzled bf16 window tiles ----------
// Tile n_local (within half-batch): 50176 B = [s:2][p:49][row 512B swizzled by p].
// Reads coalesced (784 contiguous floats per channel per window-row strip).
__global__ __launch_bounds__(256, 3) void k_pre(
    const float* __restrict__ xe, const float* __restrict__ xv,
    __bf16* __restrict__ tiles, int hb)
{
  __shared__ __align__(16) __bf16 st[32][788];  // stride 788 elems: 8B-aligned rows, low conflict
  const int t = threadIdx.x;
  const int blk = blockIdx.x;               // [0,1024)
  const int cg = blk & 7;                   // 8 groups of 32 channels
  const int wh = (blk >> 3) & 15;
  const int bl = blk >> 7;                  // [0,8)
  const int b = hb + bl;
  const int c0 = cg * 32;

  for (int s = 0; s < 2; ++s) {
    const float* src = (s == 0 ? xe : xv) + ((size_t)(b * 256 + c0) * 112 + wh * 7) * 112;
    // stage: 32 channels x 784 contiguous floats, as float4
    for (int i = t; i < 6272; i += 256) {
      int cc = i / 196;                     // 196 float4 per channel
      int rem = i - cc * 196;
      f32x4 v = *(const f32x4*)(src + cc * 12544 + rem * 4);
      bf16x4 bv;
#pragma unroll
      for (int j = 0; j < 4; ++j) bv[j] = (__bf16)v[j];
      *(bf16x4*)&st[cc][rem * 4] = bv;
    }
    __syncthreads();
    // write: 784 rows (ww,p) x 64 B (32 ch), 4 lanes per row (bf16x8 each)
    for (int j = t; j < 3136; j += 256) {
      int row = j >> 2, sub = j & 3;
      int ww = row / 49, p = row - ww * 49;
      int y = p / 7, x = ww * 7 + (p - y * 7);
      int cs = sub * 8;
      bf16x8 v;
#pragma unroll
      for (int q = 0; q < 8; ++q) v[q] = st[cs + q][y * 112 + x];
      int n = (bl * 16 + wh) * 16 + ww;
      size_t off = (size_t)n * 50176 + s * 25088 + p * 512
                 + (((c0 + cs) * 2) ^ ((p & 7) << 4));
      *(bf16x8*)((char*)tiles + off) = v;
    }
    __syncthreads();
  }
}

// ---------------- K1: per-window fused QKV projection + attention ----------------
// Staging = linear coalesced copy of pre-built swizzled tiles. 64 KiB LDS, 2 blocks/CU.
__global__ __launch_bounds__(256, 2) void k1_attn(
    const __bf16* __restrict__ tiles,
    const __bf16* __restrict__ wqb, const __bf16* __restrict__ wkb,
    const __bf16* __restrict__ wvb, const float* __restrict__ betav,
    float* __restrict__ xout, int hb)
{
  __shared__ __align__(16) __bf16 B0[16384];  // xe tile -> q [p][o] -> P
  __shared__ __align__(16) __bf16 B1[16384];  // xv tile -> k [p][o] -> v [o_loc][kp]

  const int t = threadIdx.x;
  const int n = blockIdx.x;                 // [0,2048) within half
  const int bl = n >> 8, wh = (n >> 4) & 15, ww = n & 15;
  const int b = hb + bl;
  const int y0 = wh * 7, x0 = ww * 7;

  // zero padding rows p=49..63 of both buffers
  for (int idx = t; idx < 15 * 256; idx += 256) {
    int off = (49 + (idx >> 8)) * 512 + (idx & 255) * 2;
    *(__bf16*)((char*)B0 + off) = (__bf16)0.f;
    *(__bf16*)((char*)B1 + off) = (__bf16)0.f;
  }
  // linear coalesced stage of rows 0..48 (already swizzled by k_pre)
  {
    const char* tb = (const char*)tiles + (size_t)n * 50176;
    for (int j = t; j < 3136; j += 256) {
      bf16x8 v = *(const bf16x8*)(tb + j * 16);
      char* d = (j < 1568) ? ((char*)B0 + j * 16) : ((char*)B1 + (j - 1568) * 16);
      *(bf16x8*)d = v;
    }
  }
  __syncthreads();

  const int w = t >> 6;
  const int l = t & 63;
  const int lm = l & 15, lg = l >> 4;
  const int h = w;

  // ---- pass 1 over B0 (xe): Vacc = wv'@xe, Qacc = wq@xe ----
  f32x4 vac[4][4] = {};
  {
    f32x4 qac[4][4] = {};
    proj2_mfma(wvb, wqb, B0, vac, qac, w, lm, lg);
    __syncthreads();               // all waves done reading B0
    store_pkband(B0, qac, w, lm, lg);
    COMPILER_FENCE();
  }

  // ---- pass 2 over B1 (xv): Vacc += wv'@xv, Kacc = wk@xv ----
  {
    f32x4 kac[4][4] = {};
    proj2_mfma(wvb, wkb, B1, vac, kac, w, lm, lg);
    __syncthreads();               // all waves done reading B1
    store_pkband(B1, kac, w, lm, lg);
    COMPILER_FENCE();
  }

  // ---- S = (q k^T) * 1/8 (own head bands; wave-private) ----
  f32x4 sacc[4][4] = {};
  for (int ks = 0; ks < 2; ++ks) {
    bf16x8 aq[4], bk[4];
#pragma unroll
    for (int mt = 0; mt < 4; ++mt) {
      int qp = mt * 16 + lm;
      aq[mt] = ld_s16(B0, qp * 512 + (((h * 64 + ks * 32 + lg * 8) * 2) ^ ((qp & 7) << 4)));
    }
#pragma unroll
    for (int nt = 0; nt < 4; ++nt) {
      int kp = nt * 16 + lm;
      bk[nt] = ld_s16(B1, kp * 512 + (((h * 64 + ks * 32 + lg * 8) * 2) ^ ((kp & 7) << 4)));
    }
#pragma unroll
    for (int mt = 0; mt < 4; ++mt)
#pragma unroll
      for (int nt = 0; nt < 4; ++nt)
        sacc[mt][nt] = MFMA_BF16(aq[mt], bk[nt], sacc[mt][nt]);
  }

  // ---- softmax over kpos (padding cols exact 0 in S -> masked) ----
#pragma unroll
  for (int mt = 0; mt < 4; ++mt) {
#pragma unroll
    for (int r = 0; r < 4; ++r) {
      float v0 = sacc[mt][0][r] * 0.125f;
      float v1 = sacc[mt][1][r] * 0.125f;
      float v2 = sacc[mt][2][r] * 0.125f;
      float v3 = sacc[mt][3][r] * 0.125f;
      float mx = fmaxf(fmaxf(v0, v1), fmaxf(v2, v3));
      mx = fmaxf(mx, __shfl_xor(mx, 1));
      mx = fmaxf(mx, __shfl_xor(mx, 2));
      mx = fmaxf(mx, __shfl_xor(mx, 4));
      mx = fmaxf(mx, __shfl_xor(mx, 8));
      float e0 = __expf(v0 - mx);
      float e1 = __expf(v1 - mx);
      float e2 = __expf(v2 - mx);
      float e3 = (lm == 0) ? __expf(v3 - mx) : 0.f;  // kp = 48+lm >= 49 masked
      float sum = e0 + e1 + e2 + e3;
      sum += __shfl_xor(sum, 1);
      sum += __shfl_xor(sum, 2);
      sum += __shfl_xor(sum, 4);
      sum += __shfl_xor(sum, 8);
      float inv = 1.f / sum;
      int qp = mt * 16 + lg * 4 + r;
      int base = qp * 512;
      int sw = (qp & 7) << 4;
      *(__bf16*)((char*)B0 + base + (((h * 64 + 0  + lm) * 2) ^ sw)) = (__bf16)(e0 * inv);
      *(__bf16*)((char*)B0 + base + (((h * 64 + 16 + lm) * 2) ^ sw)) = (__bf16)(e1 * inv);
      *(__bf16*)((char*)B0 + base + (((h * 64 + 32 + lm) * 2) ^ sw)) = (__bf16)(e2 * inv);
      *(__bf16*)((char*)B0 + base + (((h * 64 + 48 + lm) * 2) ^ sw)) = (__bf16)(e3 * inv);
    }
  }
  COMPILER_FENCE();

  // ---- finalize v = relu(Vacc + beta), store own band of B1: [o_local][kp] ----
  {
    float beta[4][4];
#pragma unroll
    for (int mt = 0; mt < 4; ++mt) {
      f32x4 bv = *(const f32x4*)(betav + w * 64 + mt * 16 + lg * 4);
#pragma unroll
      for (int r = 0; r < 4; ++r) beta[mt][r] = bv[r];
    }
#pragma unroll
    for (int mt = 0; mt < 4; ++mt)
#pragma unroll
      for (int nt = 0; nt < 4; ++nt)
#pragma unroll
        for (int r = 0; r < 4; ++r) {
          int ol = mt * 16 + lg * 4 + r;
          int p = nt * 16 + lm;
          float val = fmaxf(vac[mt][nt][r] + beta[mt][r], 0.f);
          int off = ol * 512 + h * 128 + ((p * 2) ^ ((ol & 7) << 4));
          *(__bf16*)((char*)B1 + off) = (__bf16)val;
        }
  }
  COMPILER_FENCE();

  // ---- x_sp = P @ v ----
  f32x4 oacc[4][4] = {};
  for (int ks = 0; ks < 2; ++ks) {
    bf16x8 ap[4], bv[4];
#pragma unroll
    for (int mt = 0; mt < 4; ++mt) {
      int qp = mt * 16 + lm;
      ap[mt] = ld_s16(B0, qp * 512 + (((h * 64 + ks * 32 + lg * 8) * 2) ^ ((qp & 7) << 4)));
    }
#pragma unroll
    for (int nt = 0; nt < 4; ++nt) {
      int ol = nt * 16 + lm;
      bv[nt] = ld_s16(B1, ol * 512 + h * 128 + (((ks * 32 + lg * 8) * 2) ^ ((ol & 7) << 4)));
    }
#pragma unroll
    for (int mt = 0; mt < 4; ++mt)
#pragma unroll
      for (int nt = 0; nt < 4; ++nt)
        oacc[mt][nt] = MFMA_BF16(ap[mt], bv[nt], oacc[mt][nt]);
  }

  // ---- store x = IMP * x_sp (fp32) ----
  const float IMP = (1.0f / 49.0f) / ((1.0f / 49.0f) + 1e-6f);
#pragma unroll
  for (int mt = 0; mt < 4; ++mt)
#pragma unroll
    for (int nt = 0; nt < 4; ++nt)
#pragma unroll
      for (int r = 0; r < 4; ++r) {
        int qp = mt * 16 + lg * 4 + r;
        if (qp < 49) {
          int c = h * 64 + nt * 16 + lm;
          int yy = y0 + qp / 7;
          int xx = x0 + qp % 7;
          xout[((size_t)(b * 256 + c) * 112 + yy) * 112 + xx] = IMP * oacc[mt][nt][r];
        }
      }
}

// ---------------- K2: depthwise 3x3 + BN2 + SiLU + pool partial (LDS-staged) ------
__global__ __launch_bounds__(256, 3) void k2_conv(
    const float* __restrict__ xin, const float* __restrict__ dww,
    const float* __restrict__ bn2s, const float* __restrict__ bn2b,
    __bf16* __restrict__ y1, float* __restrict__ pm)
{
  __shared__ __align__(16) float pl[12544];
  __shared__ float red[4];
  const int bc = blockIdx.x;
  const int c = bc & 255;
  const float* plane = xin + (size_t)bc * 12544;
  const int t = threadIdx.x;
  for (int i = t; i < 3136; i += 256)
    ((f32x4*)pl)[i] = ((const f32x4*)plane)[i];
  float wgt[9];
#pragma unroll
  for (int i = 0; i < 9; ++i) wgt[i] = dww[c * 9 + i];
  const float sc = bn2s[c], bi = bn2b[c];
  __syncthreads();
  float lsum = 0.f;
  for (int i = 0; i < 49; ++i) {
    int p = t + (i << 8);
    int y = p / 112;
    int x = p - y * 112;
    float acc = 0.f;
#pragma unroll
    for (int dy = -1; dy <= 1; ++dy) {
      int yy = y + dy;
      if (yy < 0 || yy > 111) continue;
#pragma unroll
      for (int dx = -1; dx <= 1; ++dx) {
        int xx = x + dx;
        if (xx < 0 || xx > 111) continue;
        acc += pl[yy * 112 + xx] * wgt[(dy + 1) * 3 + (dx + 1)];
      }
    }
    float u = acc * sc + bi;
    float sl = u / (1.f + __expf(-u));
    y1[(size_t)bc * 12544 + p] = (__bf16)sl;
    lsum += sl;
  }
  lsum += __shfl_xor(lsum, 1);
  lsum += __shfl_xor(lsum, 2);
  lsum += __shfl_xor(lsum, 4);
  lsum += __shfl_xor(lsum, 8);
  lsum += __shfl_xor(lsum, 16);
  lsum += __shfl_xor(lsum, 32);
  if ((t & 63) == 0) red[t >> 6] = lsum;
  __syncthreads();
  if (t == 0) pm[bc] = (red[0] + red[1] + red[2] + red[3]) * (1.0f / 12544.0f);
}

// ---------------- K3: ECA gate ----------------
__global__ void k3_eca(const float* __restrict__ pm, const float* __restrict__ ecaw,
                       float* __restrict__ gate)
{
  int b = blockIdx.x, c = threadIdx.x;
  float p0 = (c > 0) ? pm[b * 256 + c - 1] : 0.f;
  float p1 = pm[b * 256 + c];
  float p2 = (c < 255) ? pm[b * 256 + c + 1] : 0.f;
  float a = ecaw[0] * p0 + ecaw[1] * p1 + ecaw[2] * p2;
  gate[b * 256 + c] = 1.f / (1.f + __expf(-a));
}

// ---------------- K4: out(fp32, in-place) = x + wp @ (y1 * gate) ----------------
__global__ __launch_bounds__(256) void k4_out(
    const __bf16* __restrict__ y1, const float* __restrict__ gate,
    const __bf16* __restrict__ wpb, float* out_inout)
{
  __shared__ __align__(16) __bf16 bt[16384];  // [64 pos][256 ch] bf16, swizzled
  const int t = threadIdx.x;
  const int blk = blockIdx.x;
  const int b = blk / 196;
  const int s0 = (blk - b * 196) * 64;
  const int chunk = t & 7, crow = t >> 3;
#pragma unroll
  for (int cc = 0; cc < 8; ++cc) {
    int c = cc * 32 + crow;
    float g = gate[b * 256 + c];
    const __bf16* src = y1 + (size_t)(b * 256 + c) * 12544 + s0 + chunk * 8;
    bf16x8 v = *(const bf16x8*)src;
#pragma unroll
    for (int j = 0; j < 8; ++j) {
      int s = chunk * 8 + j;
      float f = (float)v[j] * g;
      *(__bf16*)((char*)bt + s * 512 + ((c * 2) ^ ((s & 7) << 4))) = (__bf16)f;
    }
  }
  __syncthreads();
  const int w = t >> 6, l = t & 63, lm = l & 15, lg = l >> 4;
  f32x4 acc[4][4] = {};
  proj_mfma(wpb, bt, acc, w, lm, lg);
#pragma unroll
  for (int mt = 0; mt < 4; ++mt)
#pragma unroll
    for (int nt = 0; nt < 4; ++nt)
#pragma unroll
      for (int r = 0; r < 4; ++r) {
        int o = w * 64 + mt * 16 + lg * 4 + r;
        int s = nt * 16 + lm;
        size_t idx = (size_t)(b * 256 + o) * 12544 + s0 + s;
        out_inout[idx] = out_inout[idx] + acc[mt][nt][r];
      }
}

// ---------------- launcher ----------------
extern "C" void kernel_launch(void* const* d_in, const int* in_sizes, int n_in,
                              void* d_out, int out_size, void* d_ws, size_t ws_size,
                              hipStream_t stream) {
  const float* x_edge = (const float*)d_in[0];
  const float* x_vit  = (const float*)d_in[1];
  const float* bn1_g  = (const float*)d_in[2];
  const float* bn1_b  = (const float*)d_in[3];
  const float* bn1_m  = (const float*)d_in[4];
  const float* bn1_v  = (const float*)d_in[5];
  const float* wq     = (const float*)d_in[6];
  const float* wk     = (const float*)d_in[7];
  const float* wv     = (const float*)d_in[8];
  const float* dw_w   = (const float*)d_in[9];
  const float* bn2_g  = (const float*)d_in[10];
  const float* bn2_b  = (const float*)d_in[11];
  const float* bn2_m  = (const float*)d_in[12];
  const float* bn2_v  = (const float*)d_in[13];
  const float* eca_w  = (const float*)d_in[14];
  const float* wp     = (const float*)d_in[15];

  float* out = (float*)d_out;  // reference output dtype is float32

  char* ws = (char*)d_ws;
  // [0, o1): half-batch window tiles (2048 * 50176 B) for k_pre/k1,
  //          later reused as y1 (bf16, 102,760,448 B) by k2/k4.
  __bf16* tiles = (__bf16*)ws;
  __bf16* y1    = (__bf16*)ws;
  const size_t o1 = 102760448;
  __bf16* wqb  = (__bf16*)(ws + o1);
  __bf16* wkb  = (__bf16*)(ws + o1 + 131072);
  __bf16* wvb  = (__bf16*)(ws + o1 + 262144);
  __bf16* wpb  = (__bf16*)(ws + o1 + 393216);
  float*  betav= (float*)(ws + o1 + 524288);
  float*  bn2s = (float*)(ws + o1 + 525312);
  float*  bn2bb= (float*)(ws + o1 + 526336);
  float*  pm   = (float*)(ws + o1 + 527360);
  float*  gate = (float*)(ws + o1 + 543744);

  hipLaunchKernelGGL(k0_setup, dim3(256), dim3(256), 0, stream,
                     wq, wk, wv, wp, bn1_g, bn1_b, bn1_m, bn1_v,
                     bn2_g, bn2_b, bn2_m, bn2_v,
                     wqb, wkb, wvb, wpb, betav, bn2s, bn2bb);
  for (int hb = 0; hb < 16; hb += 8) {
    hipLaunchKernelGGL(k_pre, dim3(1024), dim3(256), 0, stream,
                       x_edge, x_vit, tiles, hb);
    hipLaunchKernelGGL(k1_attn, dim3(2048), dim3(256), 0, stream,
                       tiles, wqb, wkb, wvb, betav, out, hb);
  }
  hipLaunchKernelGGL(k2_conv, dim3(4096), dim3(256), 0, stream,
                     out, dw_w, bn2s, bn2bb, y1, pm);
  hipLaunchKernelGGL(k3_eca, dim3(16), dim3(256), 0, stream, pm, eca_w, gate);
  hipLaunchKernelGGL(k4_out, dim3(3136), dim3(256), 0, stream,
                     y1, gate, wpb, out);
}